// Round 1
// 307.284 us; speedup vs baseline: 1.1544x; 1.1544x over previous
//
#include <hip/hip_runtime.h>
#include <hip/hip_fp16.h>

#define CH 64
#define NBUCK 1024        // buckets = dst >> 7 (128 nodes/bucket); needs N <= 131072
#define BSHIFT 7
#define BMASK 127
#define NBLK_P 128        // partition blocks; must match k_hist/k_partition/k_bucketscan

// ---- CSR build: scatter-free two-level bucket sort ------------------------

__global__ __launch_bounds__(256) void k_hist(const int* __restrict__ dst,
                                              int* __restrict__ blkhist, int E) {
    __shared__ int h[NBUCK];
    for (int i = threadIdx.x; i < NBUCK; i += blockDim.x) h[i] = 0;
    __syncthreads();
    int chunk = (E + NBLK_P - 1) / NBLK_P;
    int beg = blockIdx.x * chunk;
    int end = min(beg + chunk, E);
    for (int e = beg + threadIdx.x; e < end; e += blockDim.x)
        atomicAdd(&h[dst[e] >> BSHIFT], 1);
    __syncthreads();
    for (int i = threadIdx.x; i < NBUCK; i += blockDim.x)
        blkhist[blockIdx.x * NBUCK + i] = h[i];
}

// One wave per bucket: scan blkhist[b][t] along b (128 values, 2/lane).
__global__ __launch_bounds__(256) void k_bucketscan(const int* __restrict__ blkhist,
                                                    int* __restrict__ off_t,
                                                    int* __restrict__ tot) {
    int lane = threadIdx.x & 63;
    int t = (blockIdx.x * blockDim.x + threadIdx.x) >> 6;   // bucket id 0..1023
    int b0 = lane * 2, b1 = b0 + 1;
    int v0 = blkhist[b0 * NBUCK + t];
    int v1 = blkhist[b1 * NBUCK + t];
    int ps = v0 + v1;
    int sc = ps;
#pragma unroll
    for (int o = 1; o < 64; o <<= 1) {
        int u = __shfl_up(sc, o, 64);
        if (lane >= o) sc += u;
    }
    int excl = sc - ps;
    off_t[t * NBLK_P + b0] = excl;
    off_t[t * NBLK_P + b1] = excl + v0;
    if (lane == 63) tot[t] = sc;
}

// Single small block: exclusive scan of 1024 bucket totals -> bbase.
__global__ __launch_bounds__(1024) void k_scantot(const int* __restrict__ tot,
                                                  int* __restrict__ bbase,
                                                  int* __restrict__ row_ptr, int n) {
    __shared__ int sh[NBUCK];
    int t = threadIdx.x;
    int v = tot[t];
    sh[t] = v;
    __syncthreads();
    for (int o = 1; o < NBUCK; o <<= 1) {
        int u = (t >= o) ? sh[t - o] : 0;
        __syncthreads();
        sh[t] += u;
        __syncthreads();
    }
    bbase[t] = sh[t] - v;
    if (t == NBUCK - 1) {
        bbase[NBUCK] = sh[t];
        row_ptr[n]   = sh[t];
    }
}

__global__ __launch_bounds__(256) void k_partition(const int* __restrict__ src,
                                                   const int* __restrict__ dst,
                                                   const int* __restrict__ off_t,
                                                   const int* __restrict__ bbase,
                                                   unsigned int* __restrict__ ebuf, int E) {
    __shared__ int cur[NBUCK];
    for (int i = threadIdx.x; i < NBUCK; i += blockDim.x)
        cur[i] = bbase[i] + off_t[i * NBLK_P + blockIdx.x];
    __syncthreads();
    int chunk = (E + NBLK_P - 1) / NBLK_P;
    int beg = blockIdx.x * chunk;
    int end = min(beg + chunk, E);
    for (int e = beg + threadIdx.x; e < end; e += blockDim.x) {
        int s = src[e];
        int d = dst[e];
        int p = atomicAdd(&cur[d >> BSHIFT], 1);
        ebuf[p] = ((unsigned int)(d & BMASK) << 17) | (unsigned int)s;
    }
}

__global__ __launch_bounds__(128) void k_bucket_csr(const unsigned int* __restrict__ ebuf,
                                                    const int* __restrict__ bbase,
                                                    int* __restrict__ row_ptr,
                                                    float* __restrict__ dinv,
                                                    int* __restrict__ col, int n) {
    __shared__ int cnt[128];
    __shared__ int cur[128];
    __shared__ int sc[128];
    int t = threadIdx.x;
    int k = blockIdx.x;
    int e0 = bbase[k], e1 = bbase[k + 1];
    cnt[t] = 0;
    __syncthreads();
    for (int e = e0 + t; e < e1; e += 128)
        atomicAdd(&cnt[ebuf[e] >> 17], 1);
    __syncthreads();
    int c = cnt[t];
    sc[t] = c;
    __syncthreads();
    for (int o = 1; o < 128; o <<= 1) {
        int v = (t >= o) ? sc[t - o] : 0;
        __syncthreads();
        sc[t] += v;
        __syncthreads();
    }
    int excl = sc[t] - c;
    int node = (k << BSHIFT) + t;
    if (node < n) {
        row_ptr[node] = e0 + excl;
        dinv[node] = rsqrtf((float)(c + 1));   // +1 self-loop
    }
    cur[t] = e0 + excl;
    __syncthreads();
    for (int e = e0 + t; e < e1; e += 128) {
        unsigned int u = ebuf[e];
        int p = atomicAdd(&cur[u >> 17], 1);
        col[p] = (int)(u & 0x1FFFFu);
    }
}

// ---- GEMM: wave-per-node, W in LDS, x-row broadcast via shuffle -----------
// Writes hs[node][c] = (x @ W1)[node][c] * dinv[node]  as fp16.

__global__ __launch_bounds__(256) void k_gemm64(const float* __restrict__ in,
                                                const float* __restrict__ W,
                                                const float* __restrict__ dinv,
                                                __half* __restrict__ hs, int n) {
    __shared__ float Ws[CH * CH];
    for (int i = threadIdx.x; i < CH * CH; i += blockDim.x) Ws[i] = W[i];
    __syncthreads();

    int lane = threadIdx.x & 63;
    int wid  = (blockIdx.x * blockDim.x + threadIdx.x) >> 6;
    int nw   = (gridDim.x * blockDim.x) >> 6;

    for (int node = wid; node < n; node += nw) {
        float v = in[(size_t)node * CH + lane];
        float acc = 0.0f;
#pragma unroll
        for (int k = 0; k < CH; ++k)
            acc = fmaf(__shfl(v, k, 64), Ws[k * CH + lane], acc);
        hs[(size_t)node * CH + lane] = __float2half(acc * dinv[node]);
    }
}

// ---- fused: gather(agg1) + bias + relu + GEMM(W2) + dot(Wl) -> z ----------
// v2: TWO consecutive nodes per wave iteration (a=2p, b=2p+1):
//  * 16 gather loads in flight (8 per node) instead of 8
//  * uniform PADDED 16-row batches: self-loop folded in as row==deg, rows
//    beyond deg+1 masked out (pad loads hit the node's own L1-resident row).
//    This removes the serial 2-row tail path that carried ~45% of edges.
//  * row_ptr prefetched one grid-stride iteration ahead (hides one latency
//    stage of the rp -> col -> gather chain)
//  * joint epilogue: Ws2 LDS reads shared between both nodes; the two
//    independent cross-lane reduction chains interleave (latency amortized).
// Pad col reads stay in-bounds: they land in ebuf (allocated right after col)
// and the loaded garbage is discarded by the select before use.

__global__ __launch_bounds__(256) void k_gather_gemm(const int* __restrict__ row_ptr,
                                                     const int* __restrict__ col,
                                                     const __half2* __restrict__ hs2,
                                                     const float* __restrict__ dinv,
                                                     const float* __restrict__ W,
                                                     const float* __restrict__ bias,
                                                     const float* __restrict__ Wl,
                                                     float* __restrict__ z, int n) {
    __shared__ float Ws[CH * CH];
    for (int i = threadIdx.x; i < CH * CH; i += blockDim.x) Ws[i] = W[i];
    __syncthreads();
    const float2* Ws2 = (const float2*)Ws;

    int lane = threadIdx.x & 63;
    int l    = lane & 31;          // channel-pair index: channels 2l, 2l+1
    int g    = lane >> 5;          // half-wave: row parity
    int wid  = (blockIdx.x * blockDim.x + threadIdx.x) >> 6;
    int nw   = (gridDim.x * blockDim.x) >> 6;

    float2 wl2 = *(const float2*)(Wl + 2 * l);
    float2 bi2 = *(const float2*)(bias + 2 * l);

    int npairs = (n + 1) >> 1;

    int pr = wid;
    int rp0 = 0, rp1 = 0, rp2 = 0;
    if (pr < npairs) {
        int a0 = pr << 1;
        rp0 = row_ptr[a0];
        rp1 = row_ptr[a0 + 1];
        rp2 = row_ptr[min(a0 + 2, n)];
    }

    for (; pr < npairs; pr += nw) {
        int a = pr << 1, b = a + 1;
        bool hasB = b < n;
        int begA = rp0;
        int midA = rp1;
        int endB = hasB ? rp2 : rp1;

        // prefetch next pair's row_ptr (consumed next iteration)
        int nxt = pr + nw;
        if (nxt < npairs) {
            int a1 = nxt << 1;
            rp0 = row_ptr[a1];
            rp1 = row_ptr[a1 + 1];
            rp2 = row_ptr[min(a1 + 2, n)];
        }

        int degA = midA - begA;
        int degB = endB - midA;
        int begB = midA;

        float2 dv = *(const float2*)(dinv + (pr << 1));   // dinv[a], dinv[b]

        float2 accA = make_float2(0.f, 0.f);
        float2 accB = make_float2(0.f, 0.f);

        int degM = max(degA, degB);
        int nb = (degM + 16) >> 4;          // ceil((degM + 1) / 16) rows incl. self

        for (int t = 0; t < nb; ++t) {
            int e0 = t << 4;
            int cA[8], cB[8];
#pragma unroll
            for (int i = 0; i < 8; ++i) {
                int r = e0 + 2 * i + g;     // this half-wave's row index
                cA[i] = col[begA + r];      // may read pad (in-bounds garbage)
                cB[i] = col[begB + r];
            }
            __half2 hA[8], hB[8];
#pragma unroll
            for (int i = 0; i < 8; ++i) {
                int r = e0 + 2 * i + g;
                int iA = (r < degA) ? cA[i] : a;   // row==deg -> self-loop
                int iB = (r < degB) ? cB[i] : b;
                hA[i] = hs2[(iA << 5) + l];
                hB[i] = hs2[(iB << 5) + l];
            }
#pragma unroll
            for (int i = 0; i < 8; ++i) {
                int r = e0 + 2 * i + g;
                float2 fA = __half22float2(hA[i]);
                float2 fB = __half22float2(hB[i]);
                accA.x += (r <= degA) ? fA.x : 0.0f;
                accA.y += (r <= degA) ? fA.y : 0.0f;
                accB.x += (r <= degB) ? fB.x : 0.0f;
                accB.y += (r <= degB) ? fB.y : 0.0f;
            }
        }

        // combine the two half-wave partial sums (independent chains)
        accA.x += __shfl_xor(accA.x, 32, 64);
        accA.y += __shfl_xor(accA.y, 32, 64);
        accB.x += __shfl_xor(accB.x, 32, 64);
        accB.y += __shfl_xor(accB.y, 32, 64);

        float2 vA, vB;
        vA.x = fmaxf(fmaf(accA.x, dv.x, bi2.x), 0.0f);
        vA.y = fmaxf(fmaf(accA.y, dv.x, bi2.y), 0.0f);
        vB.x = fmaxf(fmaf(accB.x, dv.y, bi2.x), 0.0f);
        vB.y = fmaxf(fmaf(accB.y, dv.y, bi2.y), 0.0f);

        // joint W2 epilogue: Ws2 reads shared between nodes A and B.
        // acc2[c], c=2l,2l+1: half g sums k in [32g, 32g+32)
        float2 a2A = make_float2(0.f, 0.f);
        float2 a2B = make_float2(0.f, 0.f);
#pragma unroll
        for (int j = 0; j < 16; ++j) {
            int m = 16 * g + j;            // source lane holding k=2m, 2m+1
            float vAx = __shfl(vA.x, m, 64);
            float vAy = __shfl(vA.y, m, 64);
            float vBx = __shfl(vB.x, m, 64);
            float vBy = __shfl(vB.y, m, 64);
            float2 w0 = Ws2[(size_t)(2 * m + 0) * 32 + l];
            float2 w1 = Ws2[(size_t)(2 * m + 1) * 32 + l];
            a2A.x = fmaf(vAx, w0.x, a2A.x); a2A.y = fmaf(vAx, w0.y, a2A.y);
            a2A.x = fmaf(vAy, w1.x, a2A.x); a2A.y = fmaf(vAy, w1.y, a2A.y);
            a2B.x = fmaf(vBx, w0.x, a2B.x); a2B.y = fmaf(vBx, w0.y, a2B.y);
            a2B.x = fmaf(vBy, w1.x, a2B.x); a2B.y = fmaf(vBy, w1.y, a2B.y);
        }
        a2A.x += __shfl_xor(a2A.x, 32, 64);
        a2A.y += __shfl_xor(a2A.y, 32, 64);
        a2B.x += __shfl_xor(a2B.x, 32, 64);
        a2B.y += __shfl_xor(a2B.y, 32, 64);

        // z = d * (acc2 . Wl); lanes duplicated across halves -> reduce 32.
        // A/B reduction chains interleave -> cross-lane latency amortized.
        float pA = (a2A.x * wl2.x + a2A.y * wl2.y) * dv.x;
        float pB = (a2B.x * wl2.x + a2B.y * wl2.y) * dv.y;
#pragma unroll
        for (int o = 16; o > 0; o >>= 1) {
            pA += __shfl_xor(pA, o, 64);
            pB += __shfl_xor(pB, o, 64);
        }
        if (lane == 0) {
            if (hasB) *(float2*)(z + a) = make_float2(pA, pB);
            else      z[a] = pA;
        }
    }
}

// ---- head: out[n] = sigmoid(dinv[n]*(z[n]+sum z[s]) + (b2.Wl + bl)) -------

__global__ __launch_bounds__(256) void k_head(const int* __restrict__ row_ptr,
                                              const int* __restrict__ col,
                                              const float* __restrict__ z,
                                              const float* __restrict__ dinv,
                                              const float* __restrict__ b2,
                                              const float* __restrict__ Wl,
                                              const float* __restrict__ bl,
                                              float* __restrict__ out, int n) {
    int lane = threadIdx.x & 63;
    float c0 = b2[lane] * Wl[lane];
#pragma unroll
    for (int o = 32; o > 0; o >>= 1) c0 += __shfl_xor(c0, o, 64);
    c0 += bl[0];

    int tid = blockIdx.x * blockDim.x + threadIdx.x;
    int st  = gridDim.x * blockDim.x;
    for (int node = tid; node < n; node += st) {
        int beg = row_ptr[node];
        int end = row_ptr[node + 1];
        float s = z[node];
        int e = beg;
        for (; e + 4 <= end; e += 4) {
            float t0 = z[col[e]];
            float t1 = z[col[e + 1]];
            float t2 = z[col[e + 2]];
            float t3 = z[col[e + 3]];
            s += t0; s += t1; s += t2; s += t3;
        }
        for (; e < end; ++e) s += z[col[e]];
        float v = dinv[node] * s + c0;
        out[node] = 1.0f / (1.0f + expf(-v));
    }
}

// ---- launch ---------------------------------------------------------------

extern "C" void kernel_launch(void* const* d_in, const int* in_sizes, int n_in,
                              void* d_out, int out_size, void* d_ws, size_t ws_size,
                              hipStream_t stream) {
    const float* x   = (const float*)d_in[0];
    const int*   ei  = (const int*)d_in[1];   // [2, E] row-major
    const float* W1  = (const float*)d_in[2];
    const float* b1  = (const float*)d_in[3];
    const float* W2  = (const float*)d_in[4];
    const float* b2  = (const float*)d_in[5];
    const float* Wl  = (const float*)d_in[6];
    const float* bl  = (const float*)d_in[7];
    float*       out = (float*)d_out;

    const int N = in_sizes[0] / CH;
    const int E = in_sizes[1] / 2;
    const int* src = ei;
    const int* dst = ei + E;

    const size_t Npad = ((size_t)N + 511) & ~(size_t)511;
    const size_t Epad = ((size_t)E + 511) & ~(size_t)511;

    __half* A      = (__half*)d_ws;                   // N*CH halves (hs1, fp16)
    float* z       = (float*)(A + (size_t)N * CH);    // N
    float* dinv    = z + Npad;                        // N
    int*   row_ptr = (int*)(dinv + Npad);             // N+1
    int*   col     = row_ptr + Npad;                  // E
    unsigned int* ebuf = (unsigned int*)(col + Epad); // E  (also absorbs col pad reads)
    int*   blkhist = (int*)(ebuf + Epad);             // NBLK_P*NBUCK
    int*   off_t   = blkhist + NBLK_P * NBUCK;        // NBUCK*NBLK_P (transposed)
    int*   bbase   = off_t + NBLK_P * NBUCK;          // NBUCK+1
    int*   tot     = bbase + NBUCK + 64;              // NBUCK

    const int TB = 256;
    const int GRID = 2048;
    const int NB_USED = (N + BMASK) >> BSHIFT;

    // CSR build — scatter-free, no single-block serial stages
    k_hist<<<NBLK_P, TB, 0, stream>>>(dst, blkhist, E);
    k_bucketscan<<<NBUCK * 64 / TB, TB, 0, stream>>>(blkhist, off_t, tot);
    k_scantot<<<1, NBUCK, 0, stream>>>(tot, bbase, row_ptr, N);
    k_partition<<<NBLK_P, TB, 0, stream>>>(src, dst, off_t, bbase, ebuf, E);
    k_bucket_csr<<<NB_USED, 128, 0, stream>>>(ebuf, bbase, row_ptr, dinv, col, N);

    // Layer 1: A = (x @ W1) * dinv  (fp16)
    k_gemm64<<<GRID, TB, 0, stream>>>(x, W1, dinv, A, N);

    // Layer 2 fused: gather(A) -> relu(agg1+b1) @ W2 * dinv -> dot(Wl) -> z
    k_gather_gemm<<<GRID, TB, 0, stream>>>(row_ptr, col, (const __half2*)A, dinv,
                                           W2, b1, Wl, z, N);

    // Head: scalar gather over z + sigmoid
    k_head<<<(N + TB - 1) / TB, TB, 0, stream>>>(row_ptr, col, z, dinv, b2, Wl, bl, out, N);
}

// Round 2
// 274.895 us; speedup vs baseline: 1.2904x; 1.1178x over previous
//
#include <hip/hip_runtime.h>
#include <hip/hip_fp16.h>

#define CH 64
#define NBUCK 1024        // buckets = dst >> 7 (128 nodes/bucket); needs N <= 131072
#define BSHIFT 7
#define BMASK 127
#define NBLK_P 128        // partition blocks; must match k_hist/k_partition/k_bucketscan

// ---- CSR build: scatter-free two-level bucket sort ------------------------

__global__ __launch_bounds__(256) void k_hist(const int* __restrict__ dst,
                                              int* __restrict__ blkhist, int E) {
    __shared__ int h[NBUCK];
    for (int i = threadIdx.x; i < NBUCK; i += blockDim.x) h[i] = 0;
    __syncthreads();
    int chunk = (E + NBLK_P - 1) / NBLK_P;
    int beg = blockIdx.x * chunk;
    int end = min(beg + chunk, E);
    for (int e = beg + threadIdx.x; e < end; e += blockDim.x)
        atomicAdd(&h[dst[e] >> BSHIFT], 1);
    __syncthreads();
    for (int i = threadIdx.x; i < NBUCK; i += blockDim.x)
        blkhist[blockIdx.x * NBUCK + i] = h[i];
}

// One wave per bucket: scan blkhist[b][t] along b (128 values, 2/lane).
__global__ __launch_bounds__(256) void k_bucketscan(const int* __restrict__ blkhist,
                                                    int* __restrict__ off_t,
                                                    int* __restrict__ tot) {
    int lane = threadIdx.x & 63;
    int t = (blockIdx.x * blockDim.x + threadIdx.x) >> 6;   // bucket id 0..1023
    int b0 = lane * 2, b1 = b0 + 1;
    int v0 = blkhist[b0 * NBUCK + t];
    int v1 = blkhist[b1 * NBUCK + t];
    int ps = v0 + v1;
    int sc = ps;
#pragma unroll
    for (int o = 1; o < 64; o <<= 1) {
        int u = __shfl_up(sc, o, 64);
        if (lane >= o) sc += u;
    }
    int excl = sc - ps;
    off_t[t * NBLK_P + b0] = excl;
    off_t[t * NBLK_P + b1] = excl + v0;
    if (lane == 63) tot[t] = sc;
}

// Single small block: exclusive scan of 1024 bucket totals -> bbase.
__global__ __launch_bounds__(1024) void k_scantot(const int* __restrict__ tot,
                                                  int* __restrict__ bbase) {
    __shared__ int sh[NBUCK];
    int t = threadIdx.x;
    int v = tot[t];
    sh[t] = v;
    __syncthreads();
    for (int o = 1; o < NBUCK; o <<= 1) {
        int u = (t >= o) ? sh[t - o] : 0;
        __syncthreads();
        sh[t] += u;
        __syncthreads();
    }
    bbase[t] = sh[t] - v;
    if (t == NBUCK - 1) bbase[NBUCK] = sh[t];
}

__global__ __launch_bounds__(256) void k_partition(const int* __restrict__ src,
                                                   const int* __restrict__ dst,
                                                   const int* __restrict__ off_t,
                                                   const int* __restrict__ bbase,
                                                   unsigned int* __restrict__ ebuf, int E) {
    __shared__ int cur[NBUCK];
    for (int i = threadIdx.x; i < NBUCK; i += blockDim.x)
        cur[i] = bbase[i] + off_t[i * NBLK_P + blockIdx.x];
    __syncthreads();
    int chunk = (E + NBLK_P - 1) / NBLK_P;
    int beg = blockIdx.x * chunk;
    int end = min(beg + chunk, E);
    for (int e = beg + threadIdx.x; e < end; e += blockDim.x) {
        int s = src[e];
        int d = dst[e];
        int p = atomicAdd(&cur[d >> BSHIFT], 1);
        ebuf[p] = ((unsigned int)(d & BMASK) << 17) | (unsigned int)s;
    }
}

// Padded CSR: every node's list = [self, edges..., pads(NZ=n)] padded to a
// multiple of 16, minimum 32. Packed row_ptr = start | (len/16 << 24).
// Per-bucket padded base = bbase[k] + k*4096 (worst-case slack: 128 nodes * 32).
__global__ __launch_bounds__(128) void k_bucket_csr(const unsigned int* __restrict__ ebuf,
                                                    const int* __restrict__ bbase,
                                                    int* __restrict__ row_ptr,
                                                    float* __restrict__ dinv,
                                                    int* __restrict__ col, int n) {
    __shared__ int cnt[128];
    __shared__ int cur[128];
    __shared__ int sc[128];
    int t = threadIdx.x;
    int k = blockIdx.x;
    int e0 = bbase[k], e1 = bbase[k + 1];
    cnt[t] = 0;
    __syncthreads();
    for (int e = e0 + t; e < e1; e += 128)
        atomicAdd(&cnt[ebuf[e] >> 17], 1);
    __syncthreads();
    int c = cnt[t];
    int pl = (c + 16) & ~15;          // pad deg+1(self) up to multiple of 16
    if (pl < 32) pl = 32;             // minimum 32 -> branchless 32-row gather
    sc[t] = pl;
    __syncthreads();
    for (int o = 1; o < 128; o <<= 1) {
        int v = (t >= o) ? sc[t - o] : 0;
        __syncthreads();
        sc[t] += v;
        __syncthreads();
    }
    int prow = e0 + (k << 12) + sc[t] - pl;   // padded start for this node
    int node = (k << BSHIFT) + t;
    if (node < n) {
        row_ptr[node] = prow | ((pl >> 4) << 24);
        dinv[node] = rsqrtf((float)(c + 1));   // +1 self-loop
    }
    col[prow] = (node < n) ? node : n;         // self-loop first
    for (int q = c + 1; q < pl; ++q) col[prow + q] = n;   // pads -> zero row
    cur[t] = prow + 1;
    __syncthreads();
    for (int e = e0 + t; e < e1; e += 128) {
        unsigned int u = ebuf[e];
        int p = atomicAdd(&cur[u >> 17], 1);
        col[p] = (int)(u & 0x1FFFFu);
    }
}

// ---- tiny fold: wt[k] = sum_c W2[k][c] * Wl[c]  (collapses the W2 GEMM) ---

__global__ __launch_bounds__(64) void k_fold(const float* __restrict__ W2,
                                             const float* __restrict__ Wl,
                                             float* __restrict__ wt) {
    int k = threadIdx.x;
    float s = 0.0f;
#pragma unroll 8
    for (int c = 0; c < CH; ++c) s = fmaf(W2[k * CH + c], Wl[c], s);
    wt[k] = s;
}

// ---- GEMM: wave-per-node, W in LDS, x-row broadcast via shuffle -----------
// Writes hs[node][c] = (x @ W1)[node][c] * dinv[node]  as fp16; hs[n] = 0.

__global__ __launch_bounds__(256) void k_gemm64(const float* __restrict__ in,
                                                const float* __restrict__ W,
                                                const float* __restrict__ dinv,
                                                __half* __restrict__ hs, int n) {
    __shared__ float Ws[CH * CH];
    for (int i = threadIdx.x; i < CH * CH; i += blockDim.x) Ws[i] = W[i];
    if (blockIdx.x == 0 && threadIdx.x < CH)
        hs[(size_t)n * CH + threadIdx.x] = __float2half(0.0f);   // zero row (pads)
    __syncthreads();

    int lane = threadIdx.x & 63;
    int wid  = (blockIdx.x * blockDim.x + threadIdx.x) >> 6;
    int nw   = (gridDim.x * blockDim.x) >> 6;

    for (int node = wid; node < n; node += nw) {
        float v = in[(size_t)node * CH + lane];
        float acc = 0.0f;
#pragma unroll
        for (int k = 0; k < CH; ++k)
            acc = fmaf(__shfl(v, k, 64), Ws[k * CH + lane], acc);
        hs[(size_t)node * CH + lane] = __float2half(acc * dinv[node]);
    }
}

// ---- fused: gather(agg1) + bias + relu + dot(w~) -> z ---------------------
// v3: W2 folded into w~ = W2@Wl -> epilogue is a 64-dot, not a GEMV.
// Two nodes per wave iteration (half-wave 0 -> node a, half-wave 1 -> node b).
// Padded CSR makes the inner loop branchless: one coalesced col vector load
// (lane-parallel, both nodes), 32 width-32 broadcast shuffles, 32 half2
// gathers in flight, unconditional f32 accumulate (pads hit hs2[n] == 0).
// No LDS, ~64 VGPR -> full occupancy. Rare deg+1>32 nodes: uniform-branch
// overflow loop. Next pair's header + col vector prefetched.

__global__ __launch_bounds__(256) void k_gather_gemm(const int* __restrict__ row_ptr,
                                                     const int* __restrict__ col,
                                                     const __half2* __restrict__ hs2,
                                                     const float* __restrict__ dinv,
                                                     const float* __restrict__ wt,
                                                     const float* __restrict__ bias,
                                                     float* __restrict__ z, int n) {
    if (blockIdx.x == 0 && threadIdx.x == 0) z[n] = 0.0f;   // pad target for k_head
    int lane = threadIdx.x & 63;
    int l    = lane & 31;          // channel-pair index: channels 2l, 2l+1
    int g    = lane >> 5;          // half-wave: 0 -> node a, 1 -> node b
    int wid  = (blockIdx.x * blockDim.x + threadIdx.x) >> 6;
    int nw   = (gridDim.x * blockDim.x) >> 6;

    float2 wt2 = ((const float2*)wt)[l];
    float2 bi2 = ((const float2*)bias)[l];

    int npairs = (n + 1) >> 1;
    int pr = wid;
    if (pr >= npairs) return;

    unsigned pkA = (unsigned)row_ptr[pr << 1];
    unsigned pkB = (unsigned)row_ptr[min((pr << 1) + 1, n - 1)];
    int cv = col[(g ? (int)(pkB & 0xFFFFFFu) : (int)(pkA & 0xFFFFFFu)) + l];

    for (; pr < npairs; pr += nw) {
        int a = pr << 1;
        bool hasB = (a + 1) < n;
        int begA = (int)(pkA & 0xFFFFFFu), nbA = (int)(pkA >> 24);
        int begB = (int)(pkB & 0xFFFFFFu), nbB = (int)(pkB >> 24);
        int mycv = cv;
        float dA = dinv[a];
        float dB = dinv[hasB ? a + 1 : a];

        // 32 gathers in flight: instr r fetches (A row r | B row r)
        __half2 h[32];
#pragma unroll
        for (int r = 0; r < 32; ++r) {
            int idx = __shfl(mycv, r, 32);       // broadcast within each half
            h[r] = hs2[(size_t)idx * 32 + l];
        }

        // prefetch next pair header + col vector (hidden under accumulate)
        int nxt = pr + nw;
        if (nxt < npairs) {
            int a1 = nxt << 1;
            pkA = (unsigned)row_ptr[a1];
            pkB = (unsigned)row_ptr[min(a1 + 1, n - 1)];
            cv = col[(g ? (int)(pkB & 0xFFFFFFu) : (int)(pkA & 0xFFFFFFu)) + l];
        }

        // 4-way partial sums (break the serial f32 add chain)
        float ax0 = 0.f, ay0 = 0.f, ax1 = 0.f, ay1 = 0.f;
        float ax2 = 0.f, ay2 = 0.f, ax3 = 0.f, ay3 = 0.f;
#pragma unroll
        for (int r = 0; r < 32; r += 4) {
            float2 f0 = __half22float2(h[r]);
            float2 f1 = __half22float2(h[r + 1]);
            float2 f2 = __half22float2(h[r + 2]);
            float2 f3 = __half22float2(h[r + 3]);
            ax0 += f0.x; ay0 += f0.y;
            ax1 += f1.x; ay1 += f1.y;
            ax2 += f2.x; ay2 += f2.y;
            ax3 += f3.x; ay3 += f3.y;
        }
        float accx = (ax0 + ax1) + (ax2 + ax3);
        float accy = (ay0 + ay1) + (ay2 + ay3);

        int nbM = max(nbA, nbB);
        if (nbM > 2) {                      // rare heavy nodes, wave-uniform branch
            int pl = (g ? nbB : nbA) << 4;
            int bg = g ? begB : begA;
            for (int r = 32; r < pl; ++r) {
                float2 f = __half22float2(hs2[(size_t)col[bg + r] * 32 + l]);
                accx += f.x; accy += f.y;
            }
        }

        float d = g ? dB : dA;
        float vx = fmaxf(fmaf(accx, d, bi2.x), 0.0f);
        float vy = fmaxf(fmaf(accy, d, bi2.y), 0.0f);
        float p = fmaf(vx, wt2.x, vy * wt2.y);
#pragma unroll
        for (int o = 16; o > 0; o >>= 1) p += __shfl_xor(p, o, 64);
        p *= d;
        if (l == 0 && (g == 0 || hasB)) z[a + g] = p;
    }
}

// ---- head: out[n] = sigmoid(dinv[n]*(sum z over padded list) + (b2.Wl+bl)) -
// Self-loop is in the list; pads read z[n] == 0. Loop count multiple of 16.

__global__ __launch_bounds__(256) void k_head(const int* __restrict__ row_ptr,
                                              const int* __restrict__ col,
                                              const float* __restrict__ z,
                                              const float* __restrict__ dinv,
                                              const float* __restrict__ b2,
                                              const float* __restrict__ Wl,
                                              const float* __restrict__ bl,
                                              float* __restrict__ out, int n) {
    int lane = threadIdx.x & 63;
    float c0 = b2[lane] * Wl[lane];
#pragma unroll
    for (int o = 32; o > 0; o >>= 1) c0 += __shfl_xor(c0, o, 64);
    c0 += bl[0];

    int tid = blockIdx.x * blockDim.x + threadIdx.x;
    int st  = gridDim.x * blockDim.x;
    for (int node = tid; node < n; node += st) {
        unsigned pk = (unsigned)row_ptr[node];
        int beg = (int)(pk & 0xFFFFFFu);
        int m   = (int)(pk >> 24) << 4;
        float s = 0.0f;
        for (int e = 0; e < m; e += 4) {
            float t0 = z[col[beg + e]];
            float t1 = z[col[beg + e + 1]];
            float t2 = z[col[beg + e + 2]];
            float t3 = z[col[beg + e + 3]];
            s += t0; s += t1; s += t2; s += t3;
        }
        float v = dinv[node] * s + c0;
        out[node] = 1.0f / (1.0f + expf(-v));
    }
}

// ---- launch ---------------------------------------------------------------

extern "C" void kernel_launch(void* const* d_in, const int* in_sizes, int n_in,
                              void* d_out, int out_size, void* d_ws, size_t ws_size,
                              hipStream_t stream) {
    const float* x   = (const float*)d_in[0];
    const int*   ei  = (const int*)d_in[1];   // [2, E] row-major
    const float* W1  = (const float*)d_in[2];
    const float* b1  = (const float*)d_in[3];
    const float* W2  = (const float*)d_in[4];
    const float* b2  = (const float*)d_in[5];
    const float* Wl  = (const float*)d_in[6];
    const float* bl  = (const float*)d_in[7];
    float*       out = (float*)d_out;

    const int N = in_sizes[0] / CH;
    const int E = in_sizes[1] / 2;
    const int* src = ei;
    const int* dst = ei + E;

    const size_t Npad = ((size_t)N + 511) & ~(size_t)511;
    const size_t Epad = ((size_t)E + 511) & ~(size_t)511;
    const size_t COLSZ = Epad + (size_t)NBUCK * 4096 + 512;   // padded CSR capacity

    // Persistent region:
    float* z        = (float*)d_ws;                   // Npad (z[n] = 0 pad target)
    float* dinv     = z + Npad;                       // Npad
    int*   row_ptr  = (int*)(dinv + Npad);            // Npad (packed start|nb<<24)
    float* wt       = (float*)(row_ptr + Npad);       // 512 slot (w~ = W2@Wl)
    int*   col      = (int*)(wt + 512);               // COLSZ
    // Transient region (dead after k_bucket_csr) — later aliased by A:
    unsigned int* ebuf = (unsigned int*)(col + COLSZ);   // Epad
    int*   blkhist  = (int*)(ebuf + Epad);            // NBLK_P*NBUCK
    int*   off_t    = blkhist + NBLK_P * NBUCK;       // NBUCK*NBLK_P (transposed)
    int*   bbase    = off_t + NBLK_P * NBUCK;         // NBUCK+1
    int*   tot      = bbase + NBUCK + 64;             // NBUCK
    // A ((N+1) rows fp16, row n zeroed) aliases the transient region:
    __half* A       = (__half*)ebuf;

    const int TB = 256;
    const int GRID = 2048;
    const int NB_USED = (N + BMASK) >> BSHIFT;

    k_fold<<<1, 64, 0, stream>>>(W2, Wl, wt);

    // CSR build — scatter-free, no single-block serial stages
    k_hist<<<NBLK_P, TB, 0, stream>>>(dst, blkhist, E);
    k_bucketscan<<<NBUCK * 64 / TB, TB, 0, stream>>>(blkhist, off_t, tot);
    k_scantot<<<1, NBUCK, 0, stream>>>(tot, bbase);
    k_partition<<<NBLK_P, TB, 0, stream>>>(src, dst, off_t, bbase, ebuf, E);
    k_bucket_csr<<<NB_USED, 128, 0, stream>>>(ebuf, bbase, row_ptr, dinv, col, N);

    // Layer 1: A = (x @ W1) * dinv  (fp16)  [A overwrites dead ebuf region]
    k_gemm64<<<GRID, TB, 0, stream>>>(x, W1, dinv, A, N);

    // Layer 2 fused: gather(A) -> relu(agg1+b1) . w~ -> z
    k_gather_gemm<<<2 * GRID, TB, 0, stream>>>(row_ptr, col, (const __half2*)A, dinv,
                                               wt, b1, z, N);

    // Head: scalar gather over z + sigmoid
    k_head<<<(N + TB - 1) / TB, TB, 0, stream>>>(row_ptr, col, z, dinv, b2, Wl, bl, out, N);
}

// Round 3
// 214.869 us; speedup vs baseline: 1.6509x; 1.2794x over previous
//
#include <hip/hip_runtime.h>
#include <hip/hip_fp16.h>

#define CH 64
#define NBUCK 1024        // buckets = dst >> 7 (128 nodes/bucket); needs N <= 131072
#define BSHIFT 7
#define BMASK 127
#define NBLK_P 128        // partition blocks; must match k_hist/k_partition/k_bucketscan

typedef _Float16 f16x4 __attribute__((ext_vector_type(4)));
typedef float    f32x4 __attribute__((ext_vector_type(4)));

// ---- CSR build: scatter-free two-level bucket sort ------------------------

__global__ __launch_bounds__(256) void k_hist(const int* __restrict__ dst,
                                              int* __restrict__ blkhist, int E) {
    __shared__ int h[NBUCK];
    for (int i = threadIdx.x; i < NBUCK; i += blockDim.x) h[i] = 0;
    __syncthreads();
    int chunk = (E + NBLK_P - 1) / NBLK_P;
    int beg = blockIdx.x * chunk;
    int end = min(beg + chunk, E);
    for (int e = beg + threadIdx.x; e < end; e += blockDim.x)
        atomicAdd(&h[dst[e] >> BSHIFT], 1);
    __syncthreads();
    for (int i = threadIdx.x; i < NBUCK; i += blockDim.x)
        blkhist[blockIdx.x * NBUCK + i] = h[i];
}

// One wave per bucket: scan blkhist[b][t] along b (128 values, 2/lane).
__global__ __launch_bounds__(256) void k_bucketscan(const int* __restrict__ blkhist,
                                                    int* __restrict__ off_t,
                                                    int* __restrict__ tot) {
    int lane = threadIdx.x & 63;
    int t = (blockIdx.x * blockDim.x + threadIdx.x) >> 6;   // bucket id 0..1023
    int b0 = lane * 2, b1 = b0 + 1;
    int v0 = blkhist[b0 * NBUCK + t];
    int v1 = blkhist[b1 * NBUCK + t];
    int ps = v0 + v1;
    int sc = ps;
#pragma unroll
    for (int o = 1; o < 64; o <<= 1) {
        int u = __shfl_up(sc, o, 64);
        if (lane >= o) sc += u;
    }
    int excl = sc - ps;
    off_t[t * NBLK_P + b0] = excl;
    off_t[t * NBLK_P + b1] = excl + v0;
    if (lane == 63) tot[t] = sc;
}

// Single small block: exclusive scan of 1024 bucket totals -> bbase.
__global__ __launch_bounds__(1024) void k_scantot(const int* __restrict__ tot,
                                                  int* __restrict__ bbase) {
    __shared__ int sh[NBUCK];
    int t = threadIdx.x;
    int v = tot[t];
    sh[t] = v;
    __syncthreads();
    for (int o = 1; o < NBUCK; o <<= 1) {
        int u = (t >= o) ? sh[t - o] : 0;
        __syncthreads();
        sh[t] += u;
        __syncthreads();
    }
    bbase[t] = sh[t] - v;
    if (t == NBUCK - 1) bbase[NBUCK] = sh[t];
}

__global__ __launch_bounds__(256) void k_partition(const int* __restrict__ src,
                                                   const int* __restrict__ dst,
                                                   const int* __restrict__ off_t,
                                                   const int* __restrict__ bbase,
                                                   unsigned int* __restrict__ ebuf, int E) {
    __shared__ int cur[NBUCK];
    for (int i = threadIdx.x; i < NBUCK; i += blockDim.x)
        cur[i] = bbase[i] + off_t[i * NBLK_P + blockIdx.x];
    __syncthreads();
    int chunk = (E + NBLK_P - 1) / NBLK_P;
    int beg = blockIdx.x * chunk;
    int end = min(beg + chunk, E);
    for (int e = beg + threadIdx.x; e < end; e += blockDim.x) {
        int s = src[e];
        int d = dst[e];
        int p = atomicAdd(&cur[d >> BSHIFT], 1);
        ebuf[p] = ((unsigned int)(d & BMASK) << 17) | (unsigned int)s;
    }
}

// Padded CSR: every node's list = [self, edges..., pads(NZ=n)] padded to a
// multiple of 16, minimum 32. Packed row_ptr = start | (len/16 << 24).
// Per-bucket padded base = bbase[k] + k*4096 (worst-case slack: 128 nodes * 32).
__global__ __launch_bounds__(128) void k_bucket_csr(const unsigned int* __restrict__ ebuf,
                                                    const int* __restrict__ bbase,
                                                    int* __restrict__ row_ptr,
                                                    float* __restrict__ dinv,
                                                    int* __restrict__ col, int n) {
    __shared__ int cnt[128];
    __shared__ int cur[128];
    __shared__ int sc[128];
    int t = threadIdx.x;
    int k = blockIdx.x;
    int e0 = bbase[k], e1 = bbase[k + 1];
    cnt[t] = 0;
    __syncthreads();
    for (int e = e0 + t; e < e1; e += 128)
        atomicAdd(&cnt[ebuf[e] >> 17], 1);
    __syncthreads();
    int c = cnt[t];
    int pl = (c + 16) & ~15;          // pad deg+1(self) up to multiple of 16
    if (pl < 32) pl = 32;             // minimum 32 -> branchless 32-row gather
    sc[t] = pl;
    __syncthreads();
    for (int o = 1; o < 128; o <<= 1) {
        int v = (t >= o) ? sc[t - o] : 0;
        __syncthreads();
        sc[t] += v;
        __syncthreads();
    }
    int prow = e0 + (k << 12) + sc[t] - pl;   // padded start for this node
    int node = (k << BSHIFT) + t;
    if (node < n) {
        row_ptr[node] = prow | ((pl >> 4) << 24);
        dinv[node] = rsqrtf((float)(c + 1));   // +1 self-loop
    }
    col[prow] = (node < n) ? node : n;         // self-loop first
    for (int q = c + 1; q < pl; ++q) col[prow + q] = n;   // pads -> zero row
    cur[t] = prow + 1;
    __syncthreads();
    for (int e = e0 + t; e < e1; e += 128) {
        unsigned int u = ebuf[e];
        int p = atomicAdd(&cur[u >> 17], 1);
        col[p] = (int)(u & 0x1FFFFu);
    }
}

// ---- tiny fold: wt[k] = sum_c W2[k][c] * Wl[c]  (collapses the W2 GEMM) ---

__global__ __launch_bounds__(64) void k_fold(const float* __restrict__ W2,
                                             const float* __restrict__ Wl,
                                             float* __restrict__ wt) {
    int k = threadIdx.x;
    float s = 0.0f;
#pragma unroll 8
    for (int c = 0; c < CH; ++c) s = fmaf(W2[k * CH + c], Wl[c], s);
    wt[k] = s;
}

// ---- prep: pack W1 into MFMA-lane-ordered fp16 hi/lo fragments ------------
// frag f = w4*4 + t  (w4 = k-window of 16, t = 16-col tile)
// lane l, reg b  <->  W1[w4*16 + 4*(l>>4) + b][t*16 + (l&15)]
// wfrag[f*256 + l*4 + b] = hi;  wfrag[4096 + ...] = lo  (hi + lo == fp32 W1)

__global__ __launch_bounds__(256) void k_prep(const float* __restrict__ W,
                                              __half* __restrict__ wfrag) {
    for (int idx = threadIdx.x; idx < 1024; idx += 256) {
        int f = idx >> 6;
        int l = idx & 63;
        int w4 = f >> 2, t = f & 3;
        int kb = w4 * 16 + 4 * (l >> 4);
        int c  = t * 16 + (l & 15);
#pragma unroll
        for (int b = 0; b < 4; ++b) {
            float wv = W[(kb + b) * CH + c];
            __half hi = __float2half(wv);
            float lo = wv - __half2float(hi);
            wfrag[(size_t)f * 256 + l * 4 + b] = hi;
            wfrag[4096 + (size_t)f * 256 + l * 4 + b] = __float2half(lo);
        }
    }
}

// ---- Layer-1 GEMM via MFMA: hs = (x @ W1) * dinv, fp16 out ----------------
// Wave handles 16 nodes x 64 cols: 4 k-windows x 4 col-tiles.
// fp16 hi/lo split (xh@Wh + xl@Wh + xh@Wl) keeps fp32-level accuracy; f32 acc.
// No LDS at all (replaces the shuffle/LDS-pipe-bound k_gemm64: 85us -> ~10us).

__global__ __launch_bounds__(256) void k_gemm_mfma(const float* __restrict__ in,
                                                   const __half* __restrict__ wfrag,
                                                   const float* __restrict__ dinv,
                                                   __half* __restrict__ hs, int n) {
    if (blockIdx.x == 0 && threadIdx.x < CH)
        hs[(size_t)n * CH + threadIdx.x] = __float2half(0.0f);   // zero row (pads)

    int lane = threadIdx.x & 63;
    int wid  = (blockIdx.x * blockDim.x + threadIdx.x) >> 6;
    int nw   = (gridDim.x * blockDim.x) >> 6;

    const f16x4* wf = (const f16x4*)wfrag;
    f16x4 wh[16], wl[16];
#pragma unroll
    for (int f = 0; f < 16; ++f) {
        wh[f] = wf[f * 64 + lane];
        wl[f] = wf[1024 + f * 64 + lane];
    }

    int r15 = lane & 15;
    int q   = lane >> 4;
    int ngrp = (n + 15) >> 4;

    for (int g = wid; g < ngrp; g += nw) {
        int base = g << 4;
        int arow = min(base + r15, n - 1);
        const float* ap = in + (size_t)arow * CH + 4 * q;

        f32x4 acc0 = {0.f, 0.f, 0.f, 0.f};
        f32x4 acc1 = {0.f, 0.f, 0.f, 0.f};
        f32x4 acc2 = {0.f, 0.f, 0.f, 0.f};
        f32x4 acc3 = {0.f, 0.f, 0.f, 0.f};

#pragma unroll
        for (int w4 = 0; w4 < 4; ++w4) {
            float4 xv = *(const float4*)(ap + w4 * 16);
            f16x4 ah, al;
            ah[0] = (_Float16)xv.x; al[0] = (_Float16)(xv.x - (float)ah[0]);
            ah[1] = (_Float16)xv.y; al[1] = (_Float16)(xv.y - (float)ah[1]);
            ah[2] = (_Float16)xv.z; al[2] = (_Float16)(xv.z - (float)ah[2]);
            ah[3] = (_Float16)xv.w; al[3] = (_Float16)(xv.w - (float)ah[3]);

            acc0 = __builtin_amdgcn_mfma_f32_16x16x16f16(ah, wh[w4 * 4 + 0], acc0, 0, 0, 0);
            acc1 = __builtin_amdgcn_mfma_f32_16x16x16f16(ah, wh[w4 * 4 + 1], acc1, 0, 0, 0);
            acc2 = __builtin_amdgcn_mfma_f32_16x16x16f16(ah, wh[w4 * 4 + 2], acc2, 0, 0, 0);
            acc3 = __builtin_amdgcn_mfma_f32_16x16x16f16(ah, wh[w4 * 4 + 3], acc3, 0, 0, 0);
            acc0 = __builtin_amdgcn_mfma_f32_16x16x16f16(al, wh[w4 * 4 + 0], acc0, 0, 0, 0);
            acc1 = __builtin_amdgcn_mfma_f32_16x16x16f16(al, wh[w4 * 4 + 1], acc1, 0, 0, 0);
            acc2 = __builtin_amdgcn_mfma_f32_16x16x16f16(al, wh[w4 * 4 + 2], acc2, 0, 0, 0);
            acc3 = __builtin_amdgcn_mfma_f32_16x16x16f16(al, wh[w4 * 4 + 3], acc3, 0, 0, 0);
            acc0 = __builtin_amdgcn_mfma_f32_16x16x16f16(ah, wl[w4 * 4 + 0], acc0, 0, 0, 0);
            acc1 = __builtin_amdgcn_mfma_f32_16x16x16f16(ah, wl[w4 * 4 + 1], acc1, 0, 0, 0);
            acc2 = __builtin_amdgcn_mfma_f32_16x16x16f16(ah, wl[w4 * 4 + 2], acc2, 0, 0, 0);
            acc3 = __builtin_amdgcn_mfma_f32_16x16x16f16(ah, wl[w4 * 4 + 3], acc3, 0, 0, 0);
        }

#pragma unroll
        for (int b = 0; b < 4; ++b) {
            int row = base + 4 * q + b;
            if (row < n) {
                float d = dinv[row];
                size_t o = (size_t)row * CH + r15;
                hs[o +  0] = __float2half(acc0[b] * d);
                hs[o + 16] = __float2half(acc1[b] * d);
                hs[o + 32] = __float2half(acc2[b] * d);
                hs[o + 48] = __float2half(acc3[b] * d);
            }
        }
    }
}

// ---- fused: gather(agg1) + bias + relu + dot(w~) -> z ---------------------
// Two nodes per wave iteration; padded CSR -> branchless 32-row gather.

__global__ __launch_bounds__(256) void k_gather_gemm(const int* __restrict__ row_ptr,
                                                     const int* __restrict__ col,
                                                     const __half2* __restrict__ hs2,
                                                     const float* __restrict__ dinv,
                                                     const float* __restrict__ wt,
                                                     const float* __restrict__ bias,
                                                     float* __restrict__ z, int n) {
    if (blockIdx.x == 0 && threadIdx.x == 0) z[n] = 0.0f;   // pad target for k_head
    int lane = threadIdx.x & 63;
    int l    = lane & 31;          // channel-pair index: channels 2l, 2l+1
    int g    = lane >> 5;          // half-wave: 0 -> node a, 1 -> node b
    int wid  = (blockIdx.x * blockDim.x + threadIdx.x) >> 6;
    int nw   = (gridDim.x * blockDim.x) >> 6;

    float2 wt2 = ((const float2*)wt)[l];
    float2 bi2 = ((const float2*)bias)[l];

    int npairs = (n + 1) >> 1;
    int pr = wid;
    if (pr >= npairs) return;

    unsigned pkA = (unsigned)row_ptr[pr << 1];
    unsigned pkB = (unsigned)row_ptr[min((pr << 1) + 1, n - 1)];
    int cv = col[(g ? (int)(pkB & 0xFFFFFFu) : (int)(pkA & 0xFFFFFFu)) + l];

    for (; pr < npairs; pr += nw) {
        int a = pr << 1;
        bool hasB = (a + 1) < n;
        int begA = (int)(pkA & 0xFFFFFFu), nbA = (int)(pkA >> 24);
        int begB = (int)(pkB & 0xFFFFFFu), nbB = (int)(pkB >> 24);
        int mycv = cv;
        float dA = dinv[a];
        float dB = dinv[hasB ? a + 1 : a];

        // 32 gathers in flight: instr r fetches (A row r | B row r)
        __half2 h[32];
#pragma unroll
        for (int r = 0; r < 32; ++r) {
            int idx = __shfl(mycv, r, 32);       // broadcast within each half
            h[r] = hs2[(size_t)idx * 32 + l];
        }

        // prefetch next pair header + col vector (hidden under accumulate)
        int nxt = pr + nw;
        if (nxt < npairs) {
            int a1 = nxt << 1;
            pkA = (unsigned)row_ptr[a1];
            pkB = (unsigned)row_ptr[min(a1 + 1, n - 1)];
            cv = col[(g ? (int)(pkB & 0xFFFFFFu) : (int)(pkA & 0xFFFFFFu)) + l];
        }

        // 4-way partial sums (break the serial f32 add chain)
        float ax0 = 0.f, ay0 = 0.f, ax1 = 0.f, ay1 = 0.f;
        float ax2 = 0.f, ay2 = 0.f, ax3 = 0.f, ay3 = 0.f;
#pragma unroll
        for (int r = 0; r < 32; r += 4) {
            float2 f0 = __half22float2(h[r]);
            float2 f1 = __half22float2(h[r + 1]);
            float2 f2 = __half22float2(h[r + 2]);
            float2 f3 = __half22float2(h[r + 3]);
            ax0 += f0.x; ay0 += f0.y;
            ax1 += f1.x; ay1 += f1.y;
            ax2 += f2.x; ay2 += f2.y;
            ax3 += f3.x; ay3 += f3.y;
        }
        float accx = (ax0 + ax1) + (ax2 + ax3);
        float accy = (ay0 + ay1) + (ay2 + ay3);

        int nbM = max(nbA, nbB);
        if (nbM > 2) {                      // rare heavy nodes, wave-uniform branch
            int pl = (g ? nbB : nbA) << 4;
            int bg = g ? begB : begA;
            for (int r = 32; r < pl; ++r) {
                float2 f = __half22float2(hs2[(size_t)col[bg + r] * 32 + l]);
                accx += f.x; accy += f.y;
            }
        }

        float d = g ? dB : dA;
        float vx = fmaxf(fmaf(accx, d, bi2.x), 0.0f);
        float vy = fmaxf(fmaf(accy, d, bi2.y), 0.0f);
        float p = fmaf(vx, wt2.x, vy * wt2.y);
#pragma unroll
        for (int o = 16; o > 0; o >>= 1) p += __shfl_xor(p, o, 64);
        p *= d;
        if (l == 0 && (g == 0 || hasB)) z[a + g] = p;
    }
}

// ---- head: out[n] = sigmoid(dinv[n]*(sum z over padded list) + (b2.Wl+bl)) -

__global__ __launch_bounds__(256) void k_head(const int* __restrict__ row_ptr,
                                              const int* __restrict__ col,
                                              const float* __restrict__ z,
                                              const float* __restrict__ dinv,
                                              const float* __restrict__ b2,
                                              const float* __restrict__ Wl,
                                              const float* __restrict__ bl,
                                              float* __restrict__ out, int n) {
    int lane = threadIdx.x & 63;
    float c0 = b2[lane] * Wl[lane];
#pragma unroll
    for (int o = 32; o > 0; o >>= 1) c0 += __shfl_xor(c0, o, 64);
    c0 += bl[0];

    int tid = blockIdx.x * blockDim.x + threadIdx.x;
    int st  = gridDim.x * blockDim.x;
    for (int node = tid; node < n; node += st) {
        unsigned pk = (unsigned)row_ptr[node];
        int beg = (int)(pk & 0xFFFFFFu);
        int m   = (int)(pk >> 24) << 4;
        float s = 0.0f;
        for (int e = 0; e < m; e += 4) {
            float t0 = z[col[beg + e]];
            float t1 = z[col[beg + e + 1]];
            float t2 = z[col[beg + e + 2]];
            float t3 = z[col[beg + e + 3]];
            s += t0; s += t1; s += t2; s += t3;
        }
        float v = dinv[node] * s + c0;
        out[node] = 1.0f / (1.0f + expf(-v));
    }
}

// ---- launch ---------------------------------------------------------------

extern "C" void kernel_launch(void* const* d_in, const int* in_sizes, int n_in,
                              void* d_out, int out_size, void* d_ws, size_t ws_size,
                              hipStream_t stream) {
    const float* x   = (const float*)d_in[0];
    const int*   ei  = (const int*)d_in[1];   // [2, E] row-major
    const float* W1  = (const float*)d_in[2];
    const float* b1  = (const float*)d_in[3];
    const float* W2  = (const float*)d_in[4];
    const float* b2  = (const float*)d_in[5];
    const float* Wl  = (const float*)d_in[6];
    const float* bl  = (const float*)d_in[7];
    float*       out = (float*)d_out;

    const int N = in_sizes[0] / CH;
    const int E = in_sizes[1] / 2;
    const int* src = ei;
    const int* dst = ei + E;

    const size_t Npad = ((size_t)N + 511) & ~(size_t)511;
    const size_t Epad = ((size_t)E + 511) & ~(size_t)511;
    const size_t COLSZ = Epad + (size_t)NBUCK * 4096 + 512;   // padded CSR capacity

    // Persistent region:
    float* z        = (float*)d_ws;                   // Npad (z[n] = 0 pad target)
    float* dinv     = z + Npad;                       // Npad
    int*   row_ptr  = (int*)(dinv + Npad);            // Npad (packed start|nb<<24)
    float* wt       = (float*)(row_ptr + Npad);       // 512 slot (w~ = W2@Wl)
    __half* wfrag   = (__half*)(wt + 512);            // 8192 halves (W1 hi/lo frags)
    int*   col      = (int*)(wfrag + 8192);           // COLSZ
    // Transient region (dead after k_bucket_csr) — later aliased by A:
    unsigned int* ebuf = (unsigned int*)(col + COLSZ);   // Epad
    int*   blkhist  = (int*)(ebuf + Epad);            // NBLK_P*NBUCK
    int*   off_t    = blkhist + NBLK_P * NBUCK;       // NBUCK*NBLK_P (transposed)
    int*   bbase    = off_t + NBLK_P * NBUCK;         // NBUCK+1
    int*   tot      = bbase + NBUCK + 64;             // NBUCK
    // A ((N+1) rows fp16, row n zeroed) aliases the transient region:
    __half* A       = (__half*)ebuf;

    const int TB = 256;
    const int GRID = 2048;
    const int NB_USED = (N + BMASK) >> BSHIFT;

    k_fold<<<1, 64, 0, stream>>>(W2, Wl, wt);
    k_prep<<<1, 256, 0, stream>>>(W1, wfrag);

    // CSR build — scatter-free, no single-block serial stages
    k_hist<<<NBLK_P, TB, 0, stream>>>(dst, blkhist, E);
    k_bucketscan<<<NBUCK * 64 / TB, TB, 0, stream>>>(blkhist, off_t, tot);
    k_scantot<<<1, NBUCK, 0, stream>>>(tot, bbase);
    k_partition<<<NBLK_P, TB, 0, stream>>>(src, dst, off_t, bbase, ebuf, E);
    k_bucket_csr<<<NB_USED, 128, 0, stream>>>(ebuf, bbase, row_ptr, dinv, col, N);

    // Layer 1: A = (x @ W1) * dinv  (fp16, MFMA)  [A overwrites dead ebuf region]
    k_gemm_mfma<<<784, TB, 0, stream>>>(x, wfrag, dinv, A, N);

    // Layer 2 fused: gather(A) -> relu(agg1+b1) . w~ -> z
    k_gather_gemm<<<2 * GRID, TB, 0, stream>>>(row_ptr, col, (const __half2*)A, dinv,
                                               wt, b1, z, N);

    // Head: scalar gather over z + sigmoid
    k_head<<<(N + TB - 1) / TB, TB, 0, stream>>>(row_ptr, col, z, dinv, b2, Wl, bl, out, N);
}

// Round 4
// 196.506 us; speedup vs baseline: 1.8052x; 1.0935x over previous
//
#include <hip/hip_runtime.h>
#include <hip/hip_fp16.h>

#define CH 64
#define NBUCK 1024        // buckets = dst >> 7 (128 nodes/bucket); needs N <= 131072
#define BSHIFT 7
#define BMASK 127
#define NBLK_P 512        // partition blocks; must match k_hist/k_partition/k_bucketscan
#define RPMASK 0x1FFFFFu  // packed row_ptr: start in [0:21), deg in [21:32)

typedef _Float16 f16x4 __attribute__((ext_vector_type(4)));
typedef float    f32x4 __attribute__((ext_vector_type(4)));

// ---- CSR build: scatter-free two-level bucket sort ------------------------

__global__ __launch_bounds__(256) void k_hist(const int* __restrict__ dst,
                                              int* __restrict__ blkhist, int E) {
    __shared__ int h[NBUCK];
    for (int i = threadIdx.x; i < NBUCK; i += blockDim.x) h[i] = 0;
    __syncthreads();
    int chunk = (E + NBLK_P - 1) / NBLK_P;
    int beg = blockIdx.x * chunk;
    int end = min(beg + chunk, E);
    for (int e = beg + threadIdx.x; e < end; e += blockDim.x)
        atomicAdd(&h[dst[e] >> BSHIFT], 1);
    __syncthreads();
    for (int i = threadIdx.x; i < NBUCK; i += blockDim.x)
        blkhist[blockIdx.x * NBUCK + i] = h[i];
}

// One wave per bucket: scan blkhist[b][t] along b (512 values, 8/lane).
__global__ __launch_bounds__(256) void k_bucketscan(const int* __restrict__ blkhist,
                                                    int* __restrict__ off_t,
                                                    int* __restrict__ tot) {
    int lane = threadIdx.x & 63;
    int t = (blockIdx.x * blockDim.x + threadIdx.x) >> 6;   // bucket id 0..1023
    int v[8], pre[8];
    int sum = 0;
#pragma unroll
    for (int j = 0; j < 8; ++j) {
        v[j] = blkhist[(lane * 8 + j) * NBUCK + t];
        pre[j] = sum;
        sum += v[j];
    }
    int sc = sum;
#pragma unroll
    for (int o = 1; o < 64; o <<= 1) {
        int u = __shfl_up(sc, o, 64);
        if (lane >= o) sc += u;
    }
    int excl = sc - sum;
#pragma unroll
    for (int j = 0; j < 8; ++j)
        off_t[t * NBLK_P + lane * 8 + j] = excl + pre[j];
    if (lane == 63) tot[t] = sc;
}

// Single small block: exclusive scan of 1024 bucket totals -> bbase.
__global__ __launch_bounds__(1024) void k_scantot(const int* __restrict__ tot,
                                                  int* __restrict__ bbase) {
    __shared__ int sh[NBUCK];
    int t = threadIdx.x;
    int v = tot[t];
    sh[t] = v;
    __syncthreads();
    for (int o = 1; o < NBUCK; o <<= 1) {
        int u = (t >= o) ? sh[t - o] : 0;
        __syncthreads();
        sh[t] += u;
        __syncthreads();
    }
    bbase[t] = sh[t] - v;
    if (t == NBUCK - 1) bbase[NBUCK] = sh[t];
}

__global__ __launch_bounds__(256) void k_partition(const int* __restrict__ src,
                                                   const int* __restrict__ dst,
                                                   const int* __restrict__ off_t,
                                                   const int* __restrict__ bbase,
                                                   unsigned int* __restrict__ ebuf, int E) {
    __shared__ int cur[NBUCK];
    for (int i = threadIdx.x; i < NBUCK; i += blockDim.x)
        cur[i] = bbase[i] + off_t[i * NBLK_P + blockIdx.x];
    __syncthreads();
    int chunk = (E + NBLK_P - 1) / NBLK_P;
    int beg = blockIdx.x * chunk;
    int end = min(beg + chunk, E);
    for (int e = beg + threadIdx.x; e < end; e += blockDim.x) {
        int s = src[e];
        int d = dst[e];
        int p = atomicAdd(&cur[d >> BSHIFT], 1);
        ebuf[p] = ((unsigned int)(d & BMASK) << 17) | (unsigned int)s;
    }
}

// Compact CSR: col holds exactly the edges (no self, no pads).
// row_ptr[node] = start | (deg << 21).  start < E=1.6M < 2^21; deg < 2^11.
__global__ __launch_bounds__(128) void k_bucket_csr(const unsigned int* __restrict__ ebuf,
                                                    const int* __restrict__ bbase,
                                                    int* __restrict__ row_ptr,
                                                    float* __restrict__ dinv,
                                                    int* __restrict__ col, int n) {
    __shared__ int cnt[128];
    __shared__ int cur[128];
    __shared__ int sc[128];
    int t = threadIdx.x;
    int k = blockIdx.x;
    int e0 = bbase[k], e1 = bbase[k + 1];
    cnt[t] = 0;
    __syncthreads();
    for (int e = e0 + t; e < e1; e += 128)
        atomicAdd(&cnt[ebuf[e] >> 17], 1);
    __syncthreads();
    int c = cnt[t];
    sc[t] = c;
    __syncthreads();
    for (int o = 1; o < 128; o <<= 1) {
        int v = (t >= o) ? sc[t - o] : 0;
        __syncthreads();
        sc[t] += v;
        __syncthreads();
    }
    int excl = sc[t] - c;
    int prow = e0 + excl;
    int node = (k << BSHIFT) + t;
    if (node < n) {
        row_ptr[node] = prow | (c << 21);
        dinv[node] = rsqrtf((float)(c + 1));   // +1 self-loop
    }
    cur[t] = prow;
    __syncthreads();
    for (int e = e0 + t; e < e1; e += 128) {
        unsigned int u = ebuf[e];
        int p = atomicAdd(&cur[u >> 17], 1);
        col[p] = (int)(u & 0x1FFFFu);
    }
}

// ---- init: wt = W2@Wl fold + W1 MFMA-fragment pack (one launch) -----------
// wfrag layout: frag f = w4*4 + t; lane l, reg b <-> W1[w4*16+4*(l>>4)+b][t*16+(l&15)]
// hi at [f*256 + l*4 + b], lo at 4096 + same  (hi + lo == fp32 W1).

__global__ __launch_bounds__(256) void k_init(const float* __restrict__ W2,
                                              const float* __restrict__ Wl,
                                              float* __restrict__ wt,
                                              const float* __restrict__ W1,
                                              __half* __restrict__ wfrag) {
    if (threadIdx.x < 64) {
        int k = threadIdx.x;
        float s = 0.0f;
#pragma unroll 8
        for (int c = 0; c < CH; ++c) s = fmaf(W2[k * CH + c], Wl[c], s);
        wt[k] = s;
    }
    for (int idx = threadIdx.x; idx < 1024; idx += 256) {
        int f = idx >> 6;
        int l = idx & 63;
        int w4 = f >> 2, t = f & 3;
        int kb = w4 * 16 + 4 * (l >> 4);
        int c  = t * 16 + (l & 15);
#pragma unroll
        for (int b = 0; b < 4; ++b) {
            float wv = W1[(kb + b) * CH + c];
            __half hi = __float2half(wv);
            float lo = wv - __half2float(hi);
            wfrag[(size_t)f * 256 + l * 4 + b] = hi;
            wfrag[4096 + (size_t)f * 256 + l * 4 + b] = __float2half(lo);
        }
    }
}

// ---- Layer-1 GEMM via MFMA: hs = (x @ W1) * dinv, fp16 out ----------------
// Wave handles 16 nodes x 64 cols: 4 k-windows x 4 col-tiles.
// fp16 hi/lo split (xh@Wh + xl@Wh + xh@Wl) keeps fp32-level accuracy; f32 acc.

__global__ __launch_bounds__(256) void k_gemm_mfma(const float* __restrict__ in,
                                                   const __half* __restrict__ wfrag,
                                                   const float* __restrict__ dinv,
                                                   __half* __restrict__ hs, int n) {
    if (blockIdx.x == 0 && threadIdx.x < CH)
        hs[(size_t)n * CH + threadIdx.x] = __float2half(0.0f);   // zero row (pads)

    int lane = threadIdx.x & 63;
    int wid  = (blockIdx.x * blockDim.x + threadIdx.x) >> 6;
    int nw   = (gridDim.x * blockDim.x) >> 6;

    const f16x4* wf = (const f16x4*)wfrag;
    f16x4 wh[16], wl[16];
#pragma unroll
    for (int f = 0; f < 16; ++f) {
        wh[f] = wf[f * 64 + lane];
        wl[f] = wf[1024 + f * 64 + lane];
    }

    int r15 = lane & 15;
    int q   = lane >> 4;
    int ngrp = (n + 15) >> 4;

    for (int g = wid; g < ngrp; g += nw) {
        int base = g << 4;
        int arow = min(base + r15, n - 1);
        const float* ap = in + (size_t)arow * CH + 4 * q;

        f32x4 acc0 = {0.f, 0.f, 0.f, 0.f};
        f32x4 acc1 = {0.f, 0.f, 0.f, 0.f};
        f32x4 acc2 = {0.f, 0.f, 0.f, 0.f};
        f32x4 acc3 = {0.f, 0.f, 0.f, 0.f};

#pragma unroll
        for (int w4 = 0; w4 < 4; ++w4) {
            float4 xv = *(const float4*)(ap + w4 * 16);
            f16x4 ah, al;
            ah[0] = (_Float16)xv.x; al[0] = (_Float16)(xv.x - (float)ah[0]);
            ah[1] = (_Float16)xv.y; al[1] = (_Float16)(xv.y - (float)ah[1]);
            ah[2] = (_Float16)xv.z; al[2] = (_Float16)(xv.z - (float)ah[2]);
            ah[3] = (_Float16)xv.w; al[3] = (_Float16)(xv.w - (float)ah[3]);

            acc0 = __builtin_amdgcn_mfma_f32_16x16x16f16(ah, wh[w4 * 4 + 0], acc0, 0, 0, 0);
            acc1 = __builtin_amdgcn_mfma_f32_16x16x16f16(ah, wh[w4 * 4 + 1], acc1, 0, 0, 0);
            acc2 = __builtin_amdgcn_mfma_f32_16x16x16f16(ah, wh[w4 * 4 + 2], acc2, 0, 0, 0);
            acc3 = __builtin_amdgcn_mfma_f32_16x16x16f16(ah, wh[w4 * 4 + 3], acc3, 0, 0, 0);
            acc0 = __builtin_amdgcn_mfma_f32_16x16x16f16(al, wh[w4 * 4 + 0], acc0, 0, 0, 0);
            acc1 = __builtin_amdgcn_mfma_f32_16x16x16f16(al, wh[w4 * 4 + 1], acc1, 0, 0, 0);
            acc2 = __builtin_amdgcn_mfma_f32_16x16x16f16(al, wh[w4 * 4 + 2], acc2, 0, 0, 0);
            acc3 = __builtin_amdgcn_mfma_f32_16x16x16f16(al, wh[w4 * 4 + 3], acc3, 0, 0, 0);
            acc0 = __builtin_amdgcn_mfma_f32_16x16x16f16(ah, wl[w4 * 4 + 0], acc0, 0, 0, 0);
            acc1 = __builtin_amdgcn_mfma_f32_16x16x16f16(ah, wl[w4 * 4 + 1], acc1, 0, 0, 0);
            acc2 = __builtin_amdgcn_mfma_f32_16x16x16f16(ah, wl[w4 * 4 + 2], acc2, 0, 0, 0);
            acc3 = __builtin_amdgcn_mfma_f32_16x16x16f16(ah, wl[w4 * 4 + 3], acc3, 0, 0, 0);
        }

#pragma unroll
        for (int b = 0; b < 4; ++b) {
            int row = base + 4 * q + b;
            if (row < n) {
                float d = dinv[row];
                size_t o = (size_t)row * CH + r15;
                hs[o +  0] = __float2half(acc0[b] * d);
                hs[o + 16] = __float2half(acc1[b] * d);
                hs[o + 32] = __float2half(acc2[b] * d);
                hs[o + 48] = __float2half(acc3[b] * d);
            }
        }
    }
}

// ---- fused: gather(agg1) + bias + relu + dot(w~) -> z ---------------------
// Two nodes per wave iteration; compact CSR. Branchless 32-row gather via
// per-row select: idx = (r < deg) ? col[beg+r] : n  (row n is zeroed, stays
// L1-hot, so pad rows cost ~nothing). Self-loop row added in the epilogue.
// Rare deg>32 nodes: wave-uniform overflow loop.

__global__ __launch_bounds__(256) void k_gather_gemm(const int* __restrict__ row_ptr,
                                                     const int* __restrict__ col,
                                                     const __half2* __restrict__ hs2,
                                                     const float* __restrict__ dinv,
                                                     const float* __restrict__ wt,
                                                     const float* __restrict__ bias,
                                                     float* __restrict__ z, int n) {
    int lane = threadIdx.x & 63;
    int l    = lane & 31;          // channel-pair index: channels 2l, 2l+1
    int g    = lane >> 5;          // half-wave: 0 -> node a, 1 -> node b
    int wid  = (blockIdx.x * blockDim.x + threadIdx.x) >> 6;
    int nw   = (gridDim.x * blockDim.x) >> 6;

    float2 wt2 = ((const float2*)wt)[l];
    float2 bi2 = ((const float2*)bias)[l];

    int npairs = (n + 1) >> 1;
    int pr = wid;
    if (pr >= npairs) return;

    unsigned pkA = (unsigned)row_ptr[pr << 1];
    unsigned pkB = (unsigned)row_ptr[min((pr << 1) + 1, n - 1)];
    int cv = col[(int)((g ? pkB : pkA) & RPMASK) + l];

    for (; pr < npairs; pr += nw) {
        int a = pr << 1;
        bool hasB = (a + 1) < n;
        int begS = (int)((g ? pkB : pkA) & RPMASK);
        int degS = (int)((g ? pkB : pkA) >> 21);
        int degA = (int)(pkA >> 21), degB = (int)(pkB >> 21);
        int selfS = g ? (hasB ? a + 1 : a) : a;
        int mycv = cv;
        float dA = dinv[a];
        float dB = dinv[hasB ? a + 1 : a];

        // 32 gathers in flight (+1 self): instr r fetches (A row r | B row r)
        __half2 h[32];
#pragma unroll
        for (int r = 0; r < 32; ++r) {
            int cr = __shfl(mycv, r, 32);        // broadcast within each half
            int idx = (r < degS) ? cr : n;       // pads -> L1-hot zero row
            h[r] = hs2[(size_t)idx * 32 + l];
        }
        __half2 hself = hs2[(size_t)selfS * 32 + l];

        // prefetch next pair header + col vector (hidden under accumulate)
        int nxt = pr + nw;
        if (nxt < npairs) {
            int a1 = nxt << 1;
            pkA = (unsigned)row_ptr[a1];
            pkB = (unsigned)row_ptr[min(a1 + 1, n - 1)];
            cv = col[(int)((g ? pkB : pkA) & RPMASK) + l];
        }

        // 4-way partial sums (break the serial f32 add chain)
        float ax0, ay0, ax1 = 0.f, ay1 = 0.f;
        float ax2 = 0.f, ay2 = 0.f, ax3 = 0.f, ay3 = 0.f;
        {
            float2 fs = __half22float2(hself);
            ax0 = fs.x; ay0 = fs.y;
        }
#pragma unroll
        for (int r = 0; r < 32; r += 4) {
            float2 f0 = __half22float2(h[r]);
            float2 f1 = __half22float2(h[r + 1]);
            float2 f2 = __half22float2(h[r + 2]);
            float2 f3 = __half22float2(h[r + 3]);
            ax0 += f0.x; ay0 += f0.y;
            ax1 += f1.x; ay1 += f1.y;
            ax2 += f2.x; ay2 += f2.y;
            ax3 += f3.x; ay3 += f3.y;
        }
        float accx = (ax0 + ax1) + (ax2 + ax3);
        float accy = (ay0 + ay1) + (ay2 + ay3);

        if (max(degA, degB) > 32) {         // rare heavy nodes, wave-uniform branch
            for (int r = 32; r < degS; ++r) {
                float2 f = __half22float2(hs2[(size_t)col[begS + r] * 32 + l]);
                accx += f.x; accy += f.y;
            }
        }

        float d = g ? dB : dA;
        float vx = fmaxf(fmaf(accx, d, bi2.x), 0.0f);
        float vy = fmaxf(fmaf(accy, d, bi2.y), 0.0f);
        float p = fmaf(vx, wt2.x, vy * wt2.y);
#pragma unroll
        for (int o = 16; o > 0; o >>= 1) p += __shfl_xor(p, o, 64);
        p *= d;
        if (l == 0 && (g == 0 || hasB)) z[a + g] = p;
    }
}

// ---- head: out[n] = sigmoid(dinv[n]*(z[n]+sum z[s]) + (b2.Wl + bl)) -------
// Compact CSR: loop deg edges (4-unrolled) + self.

__global__ __launch_bounds__(256) void k_head(const int* __restrict__ row_ptr,
                                              const int* __restrict__ col,
                                              const float* __restrict__ z,
                                              const float* __restrict__ dinv,
                                              const float* __restrict__ b2,
                                              const float* __restrict__ Wl,
                                              const float* __restrict__ bl,
                                              float* __restrict__ out, int n) {
    int lane = threadIdx.x & 63;
    float c0 = b2[lane] * Wl[lane];
#pragma unroll
    for (int o = 32; o > 0; o >>= 1) c0 += __shfl_xor(c0, o, 64);
    c0 += bl[0];

    int tid = blockIdx.x * blockDim.x + threadIdx.x;
    int st  = gridDim.x * blockDim.x;
    for (int node = tid; node < n; node += st) {
        unsigned pk = (unsigned)row_ptr[node];
        int beg = (int)(pk & RPMASK);
        int deg = (int)(pk >> 21);
        float s = z[node];
        int e = 0;
        for (; e + 4 <= deg; e += 4) {
            float t0 = z[col[beg + e]];
            float t1 = z[col[beg + e + 1]];
            float t2 = z[col[beg + e + 2]];
            float t3 = z[col[beg + e + 3]];
            s += t0; s += t1; s += t2; s += t3;
        }
        for (; e < deg; ++e) s += z[col[beg + e]];
        float v = dinv[node] * s + c0;
        out[node] = 1.0f / (1.0f + expf(-v));
    }
}

// ---- launch ---------------------------------------------------------------

extern "C" void kernel_launch(void* const* d_in, const int* in_sizes, int n_in,
                              void* d_out, int out_size, void* d_ws, size_t ws_size,
                              hipStream_t stream) {
    const float* x   = (const float*)d_in[0];
    const int*   ei  = (const int*)d_in[1];   // [2, E] row-major
    const float* W1  = (const float*)d_in[2];
    const float* b1  = (const float*)d_in[3];
    const float* W2  = (const float*)d_in[4];
    const float* b2  = (const float*)d_in[5];
    const float* Wl  = (const float*)d_in[6];
    const float* bl  = (const float*)d_in[7];
    float*       out = (float*)d_out;

    const int N = in_sizes[0] / CH;
    const int E = in_sizes[1] / 2;
    const int* src = ei;
    const int* dst = ei + E;

    const size_t Npad = ((size_t)N + 511) & ~(size_t)511;
    const size_t Epad = ((size_t)E + 511) & ~(size_t)511;
    const size_t COLSZ = Epad + 512;          // compact CSR (+ slack for OOB-safe reads)

    // Persistent region:
    float* z        = (float*)d_ws;                   // Npad
    float* dinv     = z + Npad;                       // Npad
    int*   row_ptr  = (int*)(dinv + Npad);            // Npad (packed start|deg<<21)
    float* wt       = (float*)(row_ptr + Npad);       // 512 slot (w~ = W2@Wl)
    __half* wfrag   = (__half*)(wt + 512);            // 8192 halves (W1 hi/lo frags)
    int*   col      = (int*)(wfrag + 8192);           // COLSZ
    // Transient region (dead after k_bucket_csr) — later aliased by A:
    unsigned int* ebuf = (unsigned int*)(col + COLSZ);   // Epad
    int*   blkhist  = (int*)(ebuf + Epad);            // NBLK_P*NBUCK (2 MB)
    int*   off_t    = blkhist + (size_t)NBLK_P * NBUCK; // NBUCK*NBLK_P (2 MB)
    int*   bbase    = off_t + (size_t)NBLK_P * NBUCK; // NBUCK+1
    int*   tot      = bbase + NBUCK + 64;             // NBUCK
    // A ((N+1) rows fp16, row n zeroed) aliases the transient region:
    __half* A       = (__half*)ebuf;

    const int TB = 256;
    const int GRID = 2048;
    const int NB_USED = (N + BMASK) >> BSHIFT;

    k_init<<<1, TB, 0, stream>>>(W2, Wl, wt, W1, wfrag);

    // CSR build — scatter-free, no single-block serial stages
    k_hist<<<NBLK_P, TB, 0, stream>>>(dst, blkhist, E);
    k_bucketscan<<<NBUCK * 64 / TB, TB, 0, stream>>>(blkhist, off_t, tot);
    k_scantot<<<1, NBUCK, 0, stream>>>(tot, bbase);
    k_partition<<<NBLK_P, TB, 0, stream>>>(src, dst, off_t, bbase, ebuf, E);
    k_bucket_csr<<<NB_USED, 128, 0, stream>>>(ebuf, bbase, row_ptr, dinv, col, N);

    // Layer 1: A = (x @ W1) * dinv  (fp16, MFMA)  [A overwrites dead ebuf region]
    k_gemm_mfma<<<784, TB, 0, stream>>>(x, wfrag, dinv, A, N);

    // Layer 2 fused: gather(A) -> relu(agg1+b1) . w~ -> z
    k_gather_gemm<<<2 * GRID, TB, 0, stream>>>(row_ptr, col, (const __half2*)A, dinv,
                                               wt, b1, z, N);

    // Head: scalar gather over z + sigmoid
    k_head<<<(N + TB - 1) / TB, TB, 0, stream>>>(row_ptr, col, z, dinv, b2, Wl, bl, out, N);
}